// Round 6
// baseline (26926.404 us; speedup 1.0000x reference)
//
#include <hip/hip_runtime.h>
#include <stdint.h>

#define S_LEN 2048
#define TAGM64 0xFFFF0000FFFF0000ULL

typedef unsigned long long u64;
typedef unsigned int u32;
typedef __attribute__((ext_vector_type(8))) short short8;
typedef __attribute__((ext_vector_type(4))) float f32x4;

// u32 index into Hx/RHx/Zx: [buf 2][grp 2][m 16][col 512], word = (tag16<<16)|bf16
#define XIDX(pbuf, grp, m, c) (((((pbuf)*2 + (grp))*16 + (m))*512) + (c))

__device__ __forceinline__ unsigned short f2bf(float f) {
  union { float f; u32 u; } v; v.f = f;
  u32 u = v.u;
  u = (u + 0x7FFFu + ((u >> 16) & 1u)) >> 16;   // round-to-nearest-even
  return (unsigned short)u;
}
__device__ __forceinline__ float bf2f(u32 lo16) {
  union { u32 u; float f; } v; v.u = lo16 << 16; return v.f;
}
__device__ __forceinline__ u32 cvt2bf(float lo, float hi) {
  u32 r; asm("v_cvt_pk_bf16_f32 %0, %1, %2" : "=v"(r) : "v"(lo), "v"(hi)); return r;
}
__device__ __forceinline__ void ax_swap(u32* p, u32 v) {
  (void)__hip_atomic_exchange(p, v, __ATOMIC_RELAXED, __HIP_MEMORY_SCOPE_AGENT);
}
__device__ __forceinline__ u32 ld_u32(const u32* p) {
  return __hip_atomic_load(p, __ATOMIC_RELAXED, __HIP_MEMORY_SCOPE_AGENT);
}
__device__ __forceinline__ u64 ld_u64a(const u64* p) {
  return __hip_atomic_load(p, __ATOMIC_RELAXED, __HIP_MEMORY_SCOPE_AGENT);
}
__device__ __forceinline__ u32 detag(u64 q) {
  return (u32)(q & 0xFFFFu) | (u32)((q >> 16) & 0xFFFF0000u);
}
__device__ __forceinline__ void lds_fence() {
  asm volatile("s_waitcnt lgkmcnt(0)" ::: "memory");
}

__device__ __forceinline__ short8 mfma_bf16(short8 a, short8 b, f32x4& acc) {
  acc = __builtin_amdgcn_mfma_f32_16x16x32_bf16(a, b, acc, 0, 0, 0);
  return a;
}

// ---- prep: cast/reorder weights to bf16 in workspace --------------------
__global__ void prep_kernel(const float* __restrict__ Wz, const float* __restrict__ Wr,
                            const float* __restrict__ Wh, const float* __restrict__ W1,
                            const float* __restrict__ W2,
                            unsigned short* __restrict__ WgT,
                            unsigned short* __restrict__ W1T,
                            unsigned short* __restrict__ W2T) {
  const int total = 1536 * 576 + 512 * 512 + 64 * 512;
  for (int idx = blockIdx.x * 256 + threadIdx.x; idx < total; idx += gridDim.x * 256) {
    if (idx < 1536 * 576) {
      int row = idx / 576, k = idx % 576;
      float v;
      if (row < 512)       v = Wz[row * 576 + k];
      else if (row < 1024) v = Wr[(row - 512) * 576 + k];
      else {
        int r = row - 1024;
        v = (k < 64) ? Wh[r * 576 + 512 + k] : Wh[r * 576 + (k - 64)];
      }
      WgT[idx] = f2bf(v);
    } else if (idx < 1536 * 576 + 512 * 512) {
      int i = idx - 1536 * 576;
      W1T[i] = f2bf(W1[i]);
    } else {
      int i = idx - 1536 * 576 - 512 * 512;
      W2T[i] = f2bf(W2[i]);
    }
  }
}

// ---- recurrence: 32 WGs = 2 batch-groups x 16 column-slice WGs ----------
// Producer/consumer wave specialization, no workgroup barriers in the loop.
// A-waves (2,3): h -> (z,r) -> publish rh, z.   B-waves (0,1): rh,z -> hhat
// -> h update -> publish h.  All exchange words are (tag<<16)|bf16.
__global__ void __launch_bounds__(256, 1) recur_kernel(
    const float* __restrict__ x, const float* __restrict__ h0,
    const float* __restrict__ bz, const float* __restrict__ br,
    const float* __restrict__ bh, const unsigned short* __restrict__ WgT,
    u32* __restrict__ Hx, u32* __restrict__ RHx, u32* __restrict__ Zx,
    unsigned short* __restrict__ h_all, float* __restrict__ h_last) {
  extern __shared__ char smem[];
  unsigned short* Wf  = (unsigned short*)smem;     // 6 tiles x 18 kk x 64 x 8 bf16
  unsigned short* Ah  = Wf + 6 * 18 * 64 * 8;      // 16 kk x 64 x 8 bf16 (h tile)
  unsigned short* Arh = Ah + 16 * 64 * 8;          // 16 kk x 64 x 8 bf16 (rh tile)
  volatile u32* slots = (volatile u32*)(Arh + 16 * 64 * 8);  // [0,1]=B, [2,3]=A

  const int wg = blockIdx.x;
  const int g = wg >> 4, w = wg & 15;
  const int tid = threadIdx.x;
  const int lane = tid & 63, wave = tid >> 6;
  const int crow = (lane >> 4) << 2;   // C/D row base
  const int ccol = lane & 15;          // C/D col == A row (batch m)
  const int ko8 = (lane >> 4) << 3;    // k sub-offset

  // ---- one-time: weight fragments into LDS (read order == lane order) ----
  for (int i = tid; i < 6 * 18 * 64; i += 256) {
    int T = i / (18 * 64);
    int kk = (i >> 6) % 18;
    int l = i & 63;
    int row = (T >> 1) * 512 + w * 32 + (T & 1) * 16 + (l & 15);
    int k = kk * 32 + ((l >> 4) << 3);
    uint4 v = *(const uint4*)(WgT + (size_t)row * 576 + k);
    *(uint4*)(Wf + (size_t)i * 8) = v;
  }
  // ---- publish tagged h0 slice (tag 0, buffer 0) ----
  for (int i = tid; i < 512; i += 256) {
    int m = i >> 5, c = i & 31;
    float hv = h0[(size_t)(g * 16 + m) * 512 + w * 32 + c];
    ax_swap(Hx + XIDX(0, g, m, w * 32 + c), (u32)f2bf(hv));
  }
  if (tid < 4) slots[tid] = 0;
  __syncthreads();   // last barrier: Wf/slots ready

  const float* xrow = x + (size_t)(g * 16 + ccol) * (S_LEN * 64) + ko8;

  if (wave >= 2) {
    // ================= A-wave: z+r GEMMs, publish rh then z ================
    const int half = wave - 2;
    const int anloc = half * 16 + ccol;
    const int colA = w * 32 + anloc;
    const float brv = br[colA], bzv = bz[colA];
    const unsigned short* BZ = Wf + (size_t)half * 18 * 512 + lane * 8;
    const unsigned short* BR = Wf + (size_t)(2 + half) * 18 * 512 + lane * 8;

    for (int t = 0; t < S_LEN; ++t) {
      const int pb = t & 1;
      const u32 tag = (u32)t;
      const u64 pat = ((u64)tag << 16) | ((u64)tag << 48);
      const u32* Hgrp = Hx + XIDX(pb, g, 0, 0);

      // x(t) fragments
      short8 xa0, xa1;
      {
        const float* xp = xrow + (size_t)t * 64;
        float4 q0 = *(const float4*)(xp), q1 = *(const float4*)(xp + 4);
        float4 q2 = *(const float4*)(xp + 32), q3 = *(const float4*)(xp + 36);
        union { u32 w4[4]; short8 v; } u;
        u.w4[0] = cvt2bf(q0.x, q0.y); u.w4[1] = cvt2bf(q0.z, q0.w);
        u.w4[2] = cvt2bf(q1.x, q1.y); u.w4[3] = cvt2bf(q1.z, q1.w);
        xa0 = u.v;
        u.w4[0] = cvt2bf(q2.x, q2.y); u.w4[1] = cvt2bf(q2.z, q2.w);
        u.w4[2] = cvt2bf(q3.x, q3.y); u.w4[3] = cvt2bf(q3.z, q3.w);
        xa1 = u.v;
      }

      // ---- speculative bulk load of h half-tile, verify tags, retry ----
      u64 r[32];
      const u64* base = (const u64*)(Hgrp + ccol * 512 + half * 256 + ko8);
      for (unsigned it = 0;; ++it) {
        u64 acc = 0;
#pragma unroll
        for (int c = 0; c < 8; ++c)
#pragma unroll
          for (int q = 0; q < 4; ++q) {
            u64 v = ld_u64a(base + c * 16 + q);
            r[c * 4 + q] = v;
            acc |= v ^ pat;
          }
        if (__all((int)((acc & TAGM64) == 0ULL))) break;
        if (it > (1u << 20)) break;
        unsigned it2 = 0;   // cheap sentinel spin (8B) to avoid 8KB hot-poll
        u64 s;
        do { s = ld_u64a(base); } while ((((s ^ pat) & TAGM64) != 0ULL) && ++it2 < (1u << 22));
      }
      // ---- stage half into Ah ----
#pragma unroll
      for (int c = 0; c < 8; ++c) {
        uint4 pk;
        pk.x = detag(r[c * 4 + 0]); pk.y = detag(r[c * 4 + 1]);
        pk.z = detag(r[c * 4 + 2]); pk.w = detag(r[c * 4 + 3]);
        *(uint4*)(Ah + (size_t)((half * 8 + c) * 64 + lane) * 8) = pk;
      }
      lds_fence();
      if (lane == 0) slots[2 + half] = t + 1;
      { unsigned it = 0; while (slots[2 + (half ^ 1)] < (u32)(t + 1) && ++it < (1u << 22)) {} }
      lds_fence();

      // ---- fused z+r GEMMs ----
      f32x4 aZ = {0.f, 0.f, 0.f, 0.f}, aR = {0.f, 0.f, 0.f, 0.f};
      mfma_bf16(xa0, *(const short8*)(BZ + 0), aZ);
      mfma_bf16(xa0, *(const short8*)(BR + 0), aR);
      mfma_bf16(xa1, *(const short8*)(BZ + 512), aZ);
      mfma_bf16(xa1, *(const short8*)(BR + 512), aR);
#pragma unroll
      for (int kk = 0; kk < 16; ++kk) {
        short8 af = *(const short8*)(Ah + (size_t)(kk * 64 + lane) * 8);
        mfma_bf16(af, *(const short8*)(BZ + (size_t)(kk + 2) * 512), aZ);
        mfma_bf16(af, *(const short8*)(BR + (size_t)(kk + 2) * 512), aR);
      }

      // ---- publish rh (critical) then z ----
      float rv[4];
#pragma unroll
      for (int j = 0; j < 4; ++j) {
        rv[j] = 1.f / (1.f + __expf(-(aR[j] + brv)));
        u32 hw = *(volatile unsigned short*)(Ah +
                 (size_t)(w * 64 + ((anloc >> 3) << 4) + crow + j) * 8 + (anloc & 7));
        float rh = rv[j] * bf2f(hw);
        ax_swap(RHx + XIDX(pb, g, crow + j, colA), (tag << 16) | (u32)f2bf(rh));
      }
#pragma unroll
      for (int j = 0; j < 4; ++j) {
        float zv = 1.f / (1.f + __expf(-(aZ[j] + bzv)));
        ax_swap(Zx + XIDX(pb, g, crow + j, colA), (tag << 16) | (u32)f2bf(zv));
      }
    }
  } else {
    // ================= B-wave: hhat GEMM + state update, publish h =========
    const int nloc = wave * 16 + ccol;
    const int colB = w * 32 + nloc;
    const float bhv = bh[colB];
    const unsigned short* BH = Wf + (size_t)(4 + wave) * 18 * 512 + lane * 8;
    float hold[4];
#pragma unroll
    for (int j = 0; j < 4; ++j)
      hold[j] = h0[(size_t)(g * 16 + crow + j) * 512 + colB];

    for (int t = 0; t < S_LEN; ++t) {
      const int pb = t & 1;
      const u32 tag = (u32)t;
      const u64 pat = ((u64)tag << 16) | ((u64)tag << 48);
      const u32* RHgrp = RHx + XIDX(pb, g, 0, 0);

      short8 xa0, xa1;
      {
        const float* xp = xrow + (size_t)t * 64;
        float4 q0 = *(const float4*)(xp), q1 = *(const float4*)(xp + 4);
        float4 q2 = *(const float4*)(xp + 32), q3 = *(const float4*)(xp + 36);
        union { u32 w4[4]; short8 v; } u;
        u.w4[0] = cvt2bf(q0.x, q0.y); u.w4[1] = cvt2bf(q0.z, q0.w);
        u.w4[2] = cvt2bf(q1.x, q1.y); u.w4[3] = cvt2bf(q1.z, q1.w);
        xa0 = u.v;
        u.w4[0] = cvt2bf(q2.x, q2.y); u.w4[1] = cvt2bf(q2.z, q2.w);
        u.w4[2] = cvt2bf(q3.x, q3.y); u.w4[3] = cvt2bf(q3.z, q3.w);
        xa1 = u.v;
      }

      // ---- speculative bulk load of rh half-tile + own z words ----
      u64 r[32];
      u32 zr[4];
      const u64* base = (const u64*)(RHgrp + ccol * 512 + wave * 256 + ko8);
      const u32* zp = Zx + XIDX(pb, g, crow, colB);
      for (unsigned it = 0;; ++it) {
        u64 acc = 0;
#pragma unroll
        for (int c = 0; c < 8; ++c)
#pragma unroll
          for (int q = 0; q < 4; ++q) {
            u64 v = ld_u64a(base + c * 16 + q);
            r[c * 4 + q] = v;
            acc |= v ^ pat;
          }
#pragma unroll
        for (int j = 0; j < 4; ++j) {
          zr[j] = ld_u32(zp + j * 512);
          acc |= (u64)((zr[j] ^ (tag << 16)) & 0xFFFF0000u);
        }
        if (__all((int)((acc & TAGM64) == 0ULL))) break;
        if (it > (1u << 20)) break;
        unsigned it2 = 0;
        u64 s;
        do { s = ld_u64a(base); } while ((((s ^ pat) & TAGM64) != 0ULL) && ++it2 < (1u << 22));
      }
      // ---- stage half into Arh ----
#pragma unroll
      for (int c = 0; c < 8; ++c) {
        uint4 pk;
        pk.x = detag(r[c * 4 + 0]); pk.y = detag(r[c * 4 + 1]);
        pk.z = detag(r[c * 4 + 2]); pk.w = detag(r[c * 4 + 3]);
        *(uint4*)(Arh + (size_t)((wave * 8 + c) * 64 + lane) * 8) = pk;
      }
      lds_fence();
      if (lane == 0) slots[wave] = t + 1;
      { unsigned it = 0; while (slots[wave ^ 1] < (u32)(t + 1) && ++it < (1u << 22)) {} }
      lds_fence();

      // ---- hhat GEMM ----
      f32x4 hc = {0.f, 0.f, 0.f, 0.f};
      mfma_bf16(xa0, *(const short8*)(BH + 0), hc);
      mfma_bf16(xa1, *(const short8*)(BH + 512), hc);
#pragma unroll
      for (int kk = 0; kk < 16; ++kk) {
        short8 af = *(const short8*)(Arh + (size_t)(kk * 64 + lane) * 8);
        mfma_bf16(af, *(const short8*)(BH + (size_t)(kk + 2) * 512), hc);
      }

      // ---- update + publish h(t) with tag t+1 ----
#pragma unroll
      for (int j = 0; j < 4; ++j) {
        float e = __expf(2.f * (hc[j] + bhv));
        float hh = 1.f - 2.f / (e + 1.f);
        float zf = bf2f(zr[j] & 0xFFFFu);
        float hn = (1.f - zf) * hold[j] + zf * hh;
        hold[j] = hn;
        unsigned short hbv = f2bf(hn);
        ax_swap(Hx + XIDX(pb ^ 1, g, crow + j, colB), ((tag + 1) << 16) | hbv);
        h_all[((size_t)(g * 16 + crow + j) * S_LEN + t) * 512 + colB] = hbv;
        if (t == S_LEN - 1) h_last[(size_t)(g * 16 + crow + j) * 512 + colB] = hn;
      }
    }
  }
}

// ---- head: out = relu(h_all @ W1^T + b1) @ W2^T + b2 --------------------
__global__ void __launch_bounds__(256, 1) head_kernel(
    const unsigned short* __restrict__ h_all, const unsigned short* __restrict__ W1T,
    const unsigned short* __restrict__ W2T, const float* __restrict__ b1,
    const float* __restrict__ b2, float* __restrict__ out) {
  extern __shared__ char smem[];
  unsigned short* hs = (unsigned short*)smem;   // [64][520]
  unsigned short* act = hs + 64 * 520;          // [64][520]

  const int tid = threadIdx.x, lane = tid & 63, wave = tid >> 6;
  const int crow = (lane >> 4) << 2, ccol = lane & 15;
  const size_t row0 = (size_t)blockIdx.x * 64;

  for (int i = tid; i < 64 * 64; i += 256) {
    int r = i >> 6, c8 = i & 63;
    uint4 v = *(const uint4*)(h_all + (row0 + r) * 512 + c8 * 8);
    *(uint4*)(hs + r * 520 + c8 * 8) = v;
  }
  __syncthreads();

  f32x4 acc[8][4];
#pragma unroll
  for (int nt = 0; nt < 8; ++nt)
#pragma unroll
    for (int mt = 0; mt < 4; ++mt) acc[nt][mt] = {0.f, 0.f, 0.f, 0.f};

  for (int k = 0; k < 16; ++k) {
    short8 a[4];
#pragma unroll
    for (int mt = 0; mt < 4; ++mt)
      a[mt] = *(const short8*)(hs + (mt * 16 + ccol) * 520 + k * 32 + ((lane >> 4) << 3));
#pragma unroll
    for (int nt = 0; nt < 8; ++nt) {
      int n0 = (wave * 8 + nt) * 16;
      short8 b = *(const short8*)(W1T + (size_t)(n0 + ccol) * 512 + k * 32 + ((lane >> 4) << 3));
#pragma unroll
      for (int mt = 0; mt < 4; ++mt)
        acc[nt][mt] = __builtin_amdgcn_mfma_f32_16x16x32_bf16(a[mt], b, acc[nt][mt], 0, 0, 0);
    }
  }
#pragma unroll
  for (int nt = 0; nt < 8; ++nt) {
    int n = wave * 128 + nt * 16 + ccol;
    float bias = b1[n];
#pragma unroll
    for (int mt = 0; mt < 4; ++mt)
#pragma unroll
      for (int j = 0; j < 4; ++j) {
        float v = fmaxf(acc[nt][mt][j] + bias, 0.f);
        act[(mt * 16 + crow + j) * 520 + n] = f2bf(v);
      }
  }
  __syncthreads();
  for (int i = tid; i < 64 * 64; i += 256) {
    int r = i >> 6, c8 = i & 63;
    uint4 v = *(const uint4*)(W2T + (size_t)r * 512 + c8 * 8);
    *(uint4*)(hs + r * 520 + c8 * 8) = v;
  }
  __syncthreads();

  f32x4 acc2[4];
#pragma unroll
  for (int nt = 0; nt < 4; ++nt) acc2[nt] = {0.f, 0.f, 0.f, 0.f};
  for (int k = 0; k < 16; ++k) {
    short8 a = *(const short8*)(act + (wave * 16 + ccol) * 520 + k * 32 + ((lane >> 4) << 3));
#pragma unroll
    for (int nt = 0; nt < 4; ++nt) {
      short8 b = *(const short8*)(hs + (nt * 16 + ccol) * 520 + k * 32 + ((lane >> 4) << 3));
      acc2[nt] = __builtin_amdgcn_mfma_f32_16x16x32_bf16(a, b, acc2[nt], 0, 0, 0);
    }
  }
#pragma unroll
  for (int nt = 0; nt < 4; ++nt) {
    int o = nt * 16 + ccol;
    float bias = b2[o];
#pragma unroll
    for (int j = 0; j < 4; ++j) {
      int r = wave * 16 + crow + j;
      out[(row0 + r) * 64 + o] = acc2[nt][j] + bias;
    }
  }
}

extern "C" void kernel_launch(void* const* d_in, const int* in_sizes, int n_in,
                              void* d_out, int out_size, void* d_ws, size_t ws_size,
                              hipStream_t stream) {
  const float* x  = (const float*)d_in[0];
  const float* h0 = (const float*)d_in[1];
  const float* Wz = (const float*)d_in[2];
  const float* Wr = (const float*)d_in[3];
  const float* Wh = (const float*)d_in[4];
  const float* bz = (const float*)d_in[5];
  const float* br = (const float*)d_in[6];
  const float* bh = (const float*)d_in[7];
  const float* W1 = (const float*)d_in[8];
  const float* b1 = (const float*)d_in[9];
  const float* W2 = (const float*)d_in[10];
  const float* b2 = (const float*)d_in[11];

  char* ws = (char*)d_ws;
  size_t off = 0;
  u32* Hx  = (u32*)(ws + off); off += (size_t)2 * 2 * 16 * 512 * 4;   // 256 KB
  u32* RHx = (u32*)(ws + off); off += (size_t)2 * 2 * 16 * 512 * 4;   // 256 KB
  u32* Zx  = (u32*)(ws + off); off += (size_t)2 * 2 * 16 * 512 * 4;   // 256 KB
  unsigned short* WgT   = (unsigned short*)(ws + off); off += (size_t)1536 * 576 * 2;
  unsigned short* W1T   = (unsigned short*)(ws + off); off += (size_t)512 * 512 * 2;
  unsigned short* W2T   = (unsigned short*)(ws + off); off += (size_t)64 * 512 * 2;
  unsigned short* h_all = (unsigned short*)(ws + off); off += (size_t)32 * 2048 * 512 * 2;

  float* out = (float*)d_out;
  float* h_last = out + (size_t)32 * 2048 * 64;

  hipLaunchKernelGGL(prep_kernel, dim3(1024), dim3(256), 0, stream,
                     Wz, Wr, Wh, W1, W2, WgT, W1T, W2T);

  const int recur_lds = (6 * 18 * 64 * 8 + 2 * 16 * 64 * 8) * 2 + 32;   // 143,392 B
  hipFuncSetAttribute(reinterpret_cast<const void*>(&recur_kernel),
                      hipFuncAttributeMaxDynamicSharedMemorySize, recur_lds);
  hipLaunchKernelGGL(recur_kernel, dim3(32), dim3(256), recur_lds, stream,
                     x, h0, bz, br, bh, WgT, Hx, RHx, Zx, h_all, h_last);

  const int head_lds = 2 * 64 * 520 * 2;
  hipFuncSetAttribute(reinterpret_cast<const void*>(&head_kernel),
                      hipFuncAttributeMaxDynamicSharedMemorySize, head_lds);
  hipLaunchKernelGGL(head_kernel, dim3(1024), dim3(256), head_lds, stream,
                     h_all, W1T, W2T, b1, b2, out);
}